// Round 1
// baseline (2389.480 us; speedup 1.0000x reference)
//
#include <hip/hip_runtime.h>
#include <math.h>

// Problem constants (from reference)
#define NF        128
#define H_DIM     256
#define NA        200
#define B_SAMPLES 512
#define ALPHA_LR  0.01f
#define B_MIN_C   1e-4f

#define NTHREADS      512
#define NWAVES        (NTHREADS / 64)     // 8
#define ROWS_PER_WAVE (NA / NWAVES)       // 25

#define N_OUTER 20      // max inexact-Newton iterations (ref does 20 exact)
#define CG_MAX  48      // max PCG iterations per Newton system
#define CG_TOL2 4e-4f   // relative (M-norm) residual^2 tolerance -> eta = 0.02

// ---------- block-wide reductions (shuffle + tiny LDS) ----------
__device__ __forceinline__ float block_sum(float v, float* red, int tid) {
    int lane = tid & 63, wid = tid >> 6;
    __syncthreads();                       // protect red from previous use
    #pragma unroll
    for (int off = 32; off; off >>= 1) v += __shfl_down(v, off, 64);
    if (lane == 0) red[wid] = v;
    __syncthreads();
    float out = red[0];
    #pragma unroll
    for (int w = 1; w < NWAVES; ++w) out += red[w];
    return out;                            // same value in all threads
}

__device__ __forceinline__ float block_min(float v, float* red, int tid) {
    int lane = tid & 63, wid = tid >> 6;
    __syncthreads();
    #pragma unroll
    for (int off = 32; off; off >>= 1) v = fminf(v, __shfl_down(v, off, 64));
    if (lane == 0) red[wid] = v;
    __syncthreads();
    float out = red[0];
    #pragma unroll
    for (int w = 1; w < NWAVES; ++w) out = fminf(out, red[w]);
    return out;
}

__device__ __forceinline__ float block_max(float v, float* red, int tid) {
    int lane = tid & 63, wid = tid >> 6;
    __syncthreads();
    #pragma unroll
    for (int off = 32; off; off >>= 1) v = fmaxf(v, __shfl_down(v, off, 64));
    if (lane == 0) red[wid] = v;
    __syncthreads();
    float out = red[0];
    #pragma unroll
    for (int w = 1; w < NWAVES; ++w) out = fmaxf(out, red[w]);
    return out;
}

// ---------- batched 200x200 SGEMV: out = S * v (S global, v/out in LDS) ----
// Wave w handles 25 consecutive rows; lanes split the column dimension so
// global reads are coalesced 256B segments; shuffle-reduce per row.
__device__ __forceinline__ void matvec(const float* __restrict__ S,
                                       const float* __restrict__ v,
                                       float* __restrict__ out, int tid) {
    int lane = tid & 63, wid = tid >> 6;
    int r0 = wid * ROWS_PER_WAVE;
    for (int r = r0; r < r0 + ROWS_PER_WAVE; ++r) {
        const float* row = S + (size_t)r * NA;
        float acc = row[lane]       * v[lane]
                  + row[lane + 64]  * v[lane + 64]
                  + row[lane + 128] * v[lane + 128];
        if (lane < NA - 192) acc += row[lane + 192] * v[lane + 192];
        #pragma unroll
        for (int off = 32; off; off >>= 1) acc += __shfl_down(acc, off, 64);
        if (lane == 0) out[r] = acc;
    }
}

extern "C" __global__ __launch_bounds__(NTHREADS)
void rb_kernel(const float* __restrict__ x,  const float* __restrict__ Sigma,
               const float* __restrict__ W1, const float* __restrict__ b1,
               const float* __restrict__ W2, const float* __restrict__ b2,
               float* __restrict__ out) {
    __shared__ float xs[NF];
    __shared__ float hs[H_DIM];
    __shared__ float bc[NA];      // clamped+renormalized budgets
    __shared__ float sdiag[NA];   // diag(S)
    __shared__ float yv[NA], rv[NA], dv[NA], minv[NA];
    __shared__ float dyv[NA], pv[NA], qv[NA], zvv[NA];
    __shared__ float red[NWAVES];

    const int tid = threadIdx.x;
    const int s   = blockIdx.x;
    const float* S = Sigma + (size_t)s * NA * NA;

    // ---- MLP: h = LeakyReLU(W1 x + b1) ----
    if (tid < NF) xs[tid] = x[s * NF + tid];
    __syncthreads();

    if (tid < H_DIM) {
        const float* w = W1 + tid * NF;
        float acc = b1[tid];
        #pragma unroll 8
        for (int j = 0; j < NF; ++j) acc += w[j] * xs[j];
        hs[tid] = (acc >= 0.f) ? acc : ALPHA_LR * acc;
    }
    __syncthreads();

    // ---- logits = W2 h + b2 ; also grab diag(S) ----
    float logit = -INFINITY;
    if (tid < NA) {
        const float* w = W2 + tid * H_DIM;
        float acc = b2[tid];
        #pragma unroll 8
        for (int j = 0; j < H_DIM; ++j) acc += w[j] * hs[j];
        logit = acc;
        sdiag[tid] = S[(size_t)tid * NA + tid];
    }

    // ---- softmax -> b (output 2); clamp + renorm -> bc ----
    float mx = block_max(logit, red, tid);
    float e  = (tid < NA) ? expf(logit - mx) : 0.f;
    float es = block_sum(e, red, tid);
    float bsoft = e / es;
    if (tid < NA) out[(size_t)B_SAMPLES * NA + (size_t)s * NA + tid] = bsoft;
    float bcv = fmaxf(bsoft, B_MIN_C);
    float bs  = block_sum((tid < NA) ? bcv : 0.f, red, tid);
    if (tid < NA) bc[tid] = bcv / bs;
    __syncthreads();

    // ---- y0 = bc / sqrt(bc^T S bc) ----
    matvec(S, bc, qv, tid);
    __syncthreads();
    float quad = block_sum((tid < NA) ? bc[tid] * qv[tid] : 0.f, red, tid);
    if (tid < NA) yv[tid] = bc[tid] / sqrtf(quad);

    // ---- damped inexact Newton on  g(y) = S y - bc / y ----
    float gg0 = 0.f;
    for (int k = 0; k < N_OUTER; ++k) {
        __syncthreads();
        matvec(S, yv, qv, tid);
        __syncthreads();

        float part_gg = 0.f, part_rz = 0.f;
        if (tid < NA) {
            float y  = yv[tid], b_ = bc[tid];
            float g  = qv[tid] - b_ / y;
            float d  = b_ / (y * y);            // barrier diagonal of Hessian
            float mi = 1.f / (sdiag[tid] + d);  // Jacobi preconditioner
            float r  = -g;
            float z  = mi * r;
            rv[tid] = r; dv[tid] = d; minv[tid] = mi;
            dyv[tid] = 0.f; pv[tid] = z;
            part_gg = g * g;
            part_rz = r * z;
        }
        float gg = block_sum(part_gg, red, tid);
        float rz = block_sum(part_rz, red, tid);
        if (k == 0) gg0 = gg;
        if (gg <= 1e-12f * gg0 || gg <= 1e-20f) break;   // converged (uniform)

        // ---- Jacobi-PCG for (S + diag(d)) dy = -g ----
        float rz0 = rz;
        for (int j = 0; j < CG_MAX; ++j) {
            __syncthreads();
            matvec(S, pv, qv, tid);
            __syncthreads();
            float part_pq = 0.f;
            if (tid < NA) {
                float q = qv[tid] + dv[tid] * pv[tid];
                qv[tid] = q;
                part_pq = pv[tid] * q;
            }
            float pq    = block_sum(part_pq, red, tid);
            float alpha = rz / pq;
            float part_rz2 = 0.f;
            if (tid < NA) {
                dyv[tid] += alpha * pv[tid];
                float r = rv[tid] - alpha * qv[tid];
                rv[tid] = r;
                float z = minv[tid] * r;
                zvv[tid] = z;
                part_rz2 = r * z;
            }
            float rznew = block_sum(part_rz2, red, tid);
            if (rznew <= CG_TOL2 * rz0 || j == CG_MAX - 1) break;  // uniform
            float beta = rznew / rz;
            rz = rznew;
            if (tid < NA) pv[tid] = zvv[tid] + beta * pv[tid];
            // barrier before next matvec (top of loop) covers pv writes
        }

        // ---- damped step keeping y > 0 (matches reference semantics) ----
        float ratio = 1e30f;
        if (tid < NA) {
            float dy = dyv[tid];
            if (dy < 0.f) ratio = -yv[tid] / dy;
        }
        float mr    = block_min(ratio, red, tid);
        float tstep = fminf(1.f, 0.9f * mr);
        if (tid < NA) yv[tid] = fmaxf(yv[tid] + tstep * dyv[tid], 1e-12f);
    }

    // ---- z = y / sum(y)  (output 1) ----
    float ys = block_sum((tid < NA) ? yv[tid] : 0.f, red, tid);
    if (tid < NA) out[(size_t)s * NA + tid] = yv[tid] / ys;
}

extern "C" void kernel_launch(void* const* d_in, const int* in_sizes, int n_in,
                              void* d_out, int out_size, void* d_ws, size_t ws_size,
                              hipStream_t stream) {
    const float* x     = (const float*)d_in[0];
    const float* Sigma = (const float*)d_in[1];
    const float* W1    = (const float*)d_in[2];
    const float* b1    = (const float*)d_in[3];
    const float* W2    = (const float*)d_in[4];
    const float* b2    = (const float*)d_in[5];
    float* out = (float*)d_out;
    hipLaunchKernelGGL(rb_kernel, dim3(B_SAMPLES), dim3(NTHREADS), 0, stream,
                       x, Sigma, W1, b1, W2, b2, out);
}

// Round 2
// 943.510 us; speedup vs baseline: 2.5325x; 2.5325x over previous
//
#include <hip/hip_runtime.h>
#include <math.h>

#define NF        128
#define H_DIM     256
#define NA        200
#define B_SAMPLES 512
#define ALPHA_LR  0.01f
#define B_MIN_C   1e-4f

#define NTHREADS  512
#define NWAVES    (NTHREADS / 64)       // 8
#define ROWS_PER_WAVE (NA / NWAVES)     // 25

#define PITCH     103                   // dwords per LDS row (bf16 pairs), stride 103%32=7 -> conflict-free
#define SB_U32    (NA * PITCH)          // 20600
#define LDS_BYTES (SB_U32 * 4 + (128 + 256 + 11 * NA + NA + 8) * 4)

#define N_PH1     10                    // bf16-gradient Newton iterations (phase 1)
#define N_REFINE  3                     // exact-gradient refinement iterations
#define CG_MAX    40
#define CG_TOL2   4e-4f

// ---------- block-wide reductions ----------
__device__ __forceinline__ float block_sum(float v, float* red, int tid) {
    int lane = tid & 63, wid = tid >> 6;
    __syncthreads();
    #pragma unroll
    for (int off = 32; off; off >>= 1) v += __shfl_down(v, off, 64);
    if (lane == 0) red[wid] = v;
    __syncthreads();
    float out = red[0];
    #pragma unroll
    for (int w = 1; w < NWAVES; ++w) out += red[w];
    return out;
}
__device__ __forceinline__ float block_min(float v, float* red, int tid) {
    int lane = tid & 63, wid = tid >> 6;
    __syncthreads();
    #pragma unroll
    for (int off = 32; off; off >>= 1) v = fminf(v, __shfl_down(v, off, 64));
    if (lane == 0) red[wid] = v;
    __syncthreads();
    float out = red[0];
    #pragma unroll
    for (int w = 1; w < NWAVES; ++w) out = fminf(out, red[w]);
    return out;
}
__device__ __forceinline__ float block_max(float v, float* red, int tid) {
    int lane = tid & 63, wid = tid >> 6;
    __syncthreads();
    #pragma unroll
    for (int off = 32; off; off >>= 1) v = fmaxf(v, __shfl_down(v, off, 64));
    if (lane == 0) red[wid] = v;
    __syncthreads();
    float out = red[0];
    #pragma unroll
    for (int w = 1; w < NWAVES; ++w) out = fmaxf(out, red[w]);
    return out;
}

// ---------- bf16-LDS matvec: out = Sb * v (thread-per-row, 2 threads/row) ----
__device__ __forceinline__ void matvec_lds(const unsigned* __restrict__ Sb,
                                           const float* __restrict__ v,
                                           float* __restrict__ out,
                                           float* __restrict__ partial, int tid) {
    __syncthreads();                       // v, out-reuse visible
    const int half = tid >> 8;             // 0/1 : column halves
    const int row  = tid & 255;
    float acc = 0.f;
    if (row < NA) {
        const unsigned* rp = Sb + row * PITCH + half * 50;
        const float2*  v2 = (const float2*)v + half * 50;
        #pragma unroll 10
        for (int p = 0; p < 50; ++p) {
            unsigned u = rp[p];
            float2  vv = v2[p];            // broadcast across wave
            acc = fmaf(__uint_as_float(u << 16),         vv.x, acc);
            acc = fmaf(__uint_as_float(u & 0xffff0000u), vv.y, acc);
        }
    }
    if (half == 1 && row < NA) partial[row] = acc;
    __syncthreads();
    if (half == 0 && row < NA) out[row] = acc + partial[row];
    __syncthreads();
}

// ---------- exact fp32 matvec from global (wave-per-25-rows) ----------
__device__ __forceinline__ void matvec_global(const float* __restrict__ S,
                                              const float* __restrict__ v,
                                              float* __restrict__ out, int tid) {
    __syncthreads();
    int lane = tid & 63, wid = tid >> 6;
    int r0 = wid * ROWS_PER_WAVE;
    #pragma unroll 5
    for (int r = r0; r < r0 + ROWS_PER_WAVE; ++r) {
        const float* row = S + (size_t)r * NA;
        float acc = row[lane]       * v[lane]
                  + row[lane + 64]  * v[lane + 64]
                  + row[lane + 128] * v[lane + 128];
        if (lane < NA - 192) acc += row[lane + 192] * v[lane + 192];
        #pragma unroll
        for (int off = 32; off; off >>= 1) acc += __shfl_down(acc, off, 64);
        if (lane == 0) out[r] = acc;
    }
    __syncthreads();
}

// ---------- one damped inexact-Newton iteration; returns ||g||^2 ----------
__device__ __forceinline__ float newton_step(
        bool exact, const float* S, const unsigned* Sb,
        float* yv, const float* bcv, const float* sdiag,
        float* rv, float* dv, float* minv, float* dyv, float* pv,
        float* qv, float* zvv, float* partial, float* red, int tid) {

    if (exact) matvec_global(S, yv, qv, tid);
    else       matvec_lds(Sb, yv, qv, partial, tid);

    float part_gg = 0.f, part_rz = 0.f;
    if (tid < NA) {
        float y  = yv[tid], b_ = bcv[tid];
        float g  = qv[tid] - b_ / y;
        float d  = b_ / (y * y);
        float mi = 1.f / (sdiag[tid] + d);
        float r  = -g, z = mi * r;
        rv[tid] = r; dv[tid] = d; minv[tid] = mi;
        dyv[tid] = 0.f; pv[tid] = z;
        part_gg = g * g;
        part_rz = r * z;
    }
    float gg = block_sum(part_gg, red, tid);
    float rz = block_sum(part_rz, red, tid);
    if (gg <= 1e-24f) return gg;

    float rz0 = rz;
    for (int j = 0; j < CG_MAX; ++j) {
        matvec_lds(Sb, pv, qv, partial, tid);       // leading sync covers pv writes
        float part_pq = 0.f;
        if (tid < NA) {
            float q = qv[tid] + dv[tid] * pv[tid];
            qv[tid] = q;
            part_pq = pv[tid] * q;
        }
        float pq    = block_sum(part_pq, red, tid);
        float alpha = rz / pq;
        float part_rz2 = 0.f;
        if (tid < NA) {
            dyv[tid] += alpha * pv[tid];
            float r = rv[tid] - alpha * qv[tid];
            rv[tid] = r;
            float z = minv[tid] * r;
            zvv[tid] = z;
            part_rz2 = r * z;
        }
        float rznew = block_sum(part_rz2, red, tid);
        if (rznew <= CG_TOL2 * rz0 || j == CG_MAX - 1) break;
        float beta = rznew / rz;
        rz = rznew;
        if (tid < NA) pv[tid] = zvv[tid] + beta * pv[tid];
    }

    float ratio = 1e30f;
    if (tid < NA) {
        float dy = dyv[tid];
        if (dy < 0.f) ratio = -yv[tid] / dy;
    }
    float mr    = block_min(ratio, red, tid);
    float tstep = fminf(1.f, 0.9f * mr);
    if (tid < NA) yv[tid] = fmaxf(yv[tid] + tstep * dyv[tid], 1e-12f);
    return gg;
}

extern "C" __global__ __launch_bounds__(NTHREADS)
void rb_kernel(const float* __restrict__ x,  const float* __restrict__ Sigma,
               const float* __restrict__ W1, const float* __restrict__ b1,
               const float* __restrict__ W2, const float* __restrict__ b2,
               float* __restrict__ out) {
    extern __shared__ char smem[];
    unsigned* Sb  = (unsigned*)smem;                 // 200 x 103 packed bf16 pairs
    float* fb     = (float*)(smem + SB_U32 * 4);
    float* xs = fb;            float* hs = xs + 128;
    float* bcv = hs + 256;     float* sdiag = bcv + NA;
    float* yv = sdiag + NA;    float* rv = yv + NA;
    float* dv = rv + NA;       float* minv = dv + NA;
    float* dyv = minv + NA;    float* pv = dyv + NA;
    float* qv = pv + NA;       float* zvv = qv + NA;
    float* partial = zvv + NA; float* red = partial + NA;   // 8 floats

    const int tid = threadIdx.x;
    const int s   = blockIdx.x;
    const float* S = Sigma + (size_t)s * NA * NA;

    // ---- stage Sigma -> LDS as packed bf16 pairs (RNE) ----
    const float2* Sg2 = (const float2*)S;            // row pitch = 100 float2
    for (int i = tid; i < NA * 100; i += NTHREADS) {
        int r = i / 100, p = i - r * 100;
        float2 w = Sg2[i];
        unsigned bx = __float_as_uint(w.x); bx = (bx + 0x7fffu + ((bx >> 16) & 1u)) >> 16;
        unsigned by = __float_as_uint(w.y); by = (by + 0x7fffu + ((by >> 16) & 1u)) >> 16;
        Sb[r * PITCH + p] = bx | (by << 16);
    }
    if (tid < NF) xs[tid] = x[s * NF + tid];
    if (tid < NA) sdiag[tid] = S[(size_t)tid * NA + tid];
    __syncthreads();

    // ---- MLP ----
    if (tid < H_DIM) {
        const float* w = W1 + tid * NF;
        float acc = b1[tid];
        #pragma unroll 8
        for (int j = 0; j < NF; ++j) acc += w[j] * xs[j];
        hs[tid] = (acc >= 0.f) ? acc : ALPHA_LR * acc;
    }
    __syncthreads();
    float logit = -INFINITY;
    if (tid < NA) {
        const float* w = W2 + tid * H_DIM;
        float acc = b2[tid];
        #pragma unroll 8
        for (int j = 0; j < H_DIM; ++j) acc += w[j] * hs[j];
        logit = acc;
    }

    // ---- softmax -> b out; clamp + renorm -> bc ----
    float mx = block_max(logit, red, tid);
    float e  = (tid < NA) ? expf(logit - mx) : 0.f;
    float es = block_sum(e, red, tid);
    float bsoft = e / es;
    if (tid < NA) out[(size_t)B_SAMPLES * NA + (size_t)s * NA + tid] = bsoft;
    float bcl = fmaxf(bsoft, B_MIN_C);
    float bs  = block_sum((tid < NA) ? bcl : 0.f, red, tid);
    if (tid < NA) bcv[tid] = bcl / bs;

    // ---- y0 = bc / sqrt(bc^T S bc) (bf16 ok) ----
    matvec_lds(Sb, bcv, qv, partial, tid);
    float quad = block_sum((tid < NA) ? bcv[tid] * qv[tid] : 0.f, red, tid);
    if (tid < NA) yv[tid] = bcv[tid] / sqrtf(quad);

    // ---- phase 1: Newton with bf16 gradient + bf16 CG ----
    float gg0 = 0.f;
    for (int k = 0; k < N_PH1; ++k) {
        float gg = newton_step(false, S, Sb, yv, bcv, sdiag, rv, dv, minv,
                               dyv, pv, qv, zvv, partial, red, tid);
        if (k == 0) gg0 = gg;
        if (gg <= 1e-10f * gg0 || gg <= 1e-24f) break;
    }
    // ---- phase 2: exact-gradient refinement (fixed count) ----
    for (int k = 0; k < N_REFINE; ++k) {
        newton_step(true, S, Sb, yv, bcv, sdiag, rv, dv, minv,
                    dyv, pv, qv, zvv, partial, red, tid);
    }

    // ---- z = y / sum(y) ----
    float ys = block_sum((tid < NA) ? yv[tid] : 0.f, red, tid);
    if (tid < NA) out[(size_t)s * NA + tid] = yv[tid] / ys;
}

extern "C" void kernel_launch(void* const* d_in, const int* in_sizes, int n_in,
                              void* d_out, int out_size, void* d_ws, size_t ws_size,
                              hipStream_t stream) {
    const float* x     = (const float*)d_in[0];
    const float* Sigma = (const float*)d_in[1];
    const float* W1    = (const float*)d_in[2];
    const float* b1    = (const float*)d_in[3];
    const float* W2    = (const float*)d_in[4];
    const float* b2    = (const float*)d_in[5];
    float* out = (float*)d_out;
    static int attr_set = 0;
    if (!attr_set) {  // host-side config, safe under graph capture (not a stream op)
        hipFuncSetAttribute((const void*)rb_kernel,
                            hipFuncAttributeMaxDynamicSharedMemorySize, LDS_BYTES);
        attr_set = 1;
    }
    hipLaunchKernelGGL(rb_kernel, dim3(B_SAMPLES), dim3(NTHREADS), LDS_BYTES, stream,
                       x, Sigma, W1, b1, W2, b2, out);
}

// Round 3
// 570.137 us; speedup vs baseline: 4.1911x; 1.6549x over previous
//
#include <hip/hip_runtime.h>
#include <math.h>

#define NF        128
#define H_DIM     256
#define NA        200
#define B_SAMPLES 512
#define ALPHA_LR  0.01f
#define B_MIN_C   1e-4f

#define NTHREADS  512
#define NWAVES    8
#define ROWS_PER_WAVE 25          // exact-path: 8 waves x 25 rows
#define CPITCH    103             // staging pitch (dwords), 103%32=7 -> conflict-free
#define CHUNK_ROWS 64

#define N_PH1     10
#define N_REFINE  3
#define CG_MAX    40
#define TOL2_LO   4e-4f
#define TOL2_HI   2.5e-2f

// ---------------- wave-level primitives ----------------
__device__ __forceinline__ float wave_sum(float v){
  #pragma unroll
  for(int o=32;o;o>>=1) v += __shfl_down(v,o,64);
  return v;
}
__device__ __forceinline__ float wave_min(float v){
  #pragma unroll
  for(int o=32;o;o>>=1) v = fminf(v,__shfl_down(v,o,64));
  return v;
}
__device__ __forceinline__ float wave_max(float v){
  #pragma unroll
  for(int o=32;o;o>>=1) v = fmaxf(v,__shfl_down(v,o,64));
  return v;
}
// full-block reductions (prologue/softmax only)
__device__ __forceinline__ float block_sum8(float v, float* red8, int tid){
  int lane=tid&63, wid=tid>>6;
  __syncthreads();
  v = wave_sum(v);
  if(lane==0) red8[wid]=v;
  __syncthreads();
  float o=red8[0];
  #pragma unroll
  for(int w=1;w<NWAVES;++w) o+=red8[w];
  return o;
}
__device__ __forceinline__ float block_max8(float v, float* red8, int tid){
  int lane=tid&63, wid=tid>>6;
  __syncthreads();
  v = wave_max(v);
  if(lane==0) red8[wid]=v;
  __syncthreads();
  float o=red8[0];
  #pragma unroll
  for(int w=1;w<NWAVES;++w) o=fmaxf(o,red8[w]);
  return o;
}

// ---- bf16 register-matrix matvec: returns q (valid for owner = half0/act) ----
// Barriers: B1 (entry, makes v visible), B2 (partial). 2 barriers total.
__device__ __forceinline__ float matvec_reg(const unsigned* mreg,
                                            const float* __restrict__ vv,
                                            float* __restrict__ partial,
                                            int tid, int row, int half, bool act){
  __syncthreads();                                   // B1
  float a0=0.f, a1=0.f;
  if (act){
    const float2* v2 = (const float2*)vv + half*50;
    #pragma unroll
    for (int p=0;p<50;++p){
      unsigned u = mreg[p];
      float2  x = v2[p];                             // broadcast ds_read_b64
      a0 = fmaf(__uint_as_float(u<<16),          x.x, a0);
      a1 = fmaf(__uint_as_float(u&0xffff0000u),  x.y, a1);
    }
  }
  float acc = a0+a1;
  if (half==1 && act) partial[row]=acc;
  __syncthreads();                                   // B2
  return (half==0 && act) ? (acc + partial[row]) : 0.f;
}

// ---- exact fp32 matvec from global (refinement gradient only) ----
__device__ __forceinline__ float matvec_exact(const float* __restrict__ S,
                                              const float* __restrict__ vv,
                                              float* __restrict__ gq, int tid){
  __syncthreads();                                   // v visible
  int lane=tid&63, wid=tid>>6;
  int r0=wid*ROWS_PER_WAVE;
  for(int r=r0;r<r0+ROWS_PER_WAVE;++r){
    const float* rowp = S + (size_t)r*NA;
    float acc = rowp[lane]*vv[lane] + rowp[lane+64]*vv[lane+64]
              + rowp[lane+128]*vv[lane+128];
    if (lane < NA-192) acc += rowp[lane+192]*vv[lane+192];
    acc = wave_sum(acc);
    if(lane==0) gq[r]=acc;
  }
  __syncthreads();
  return (tid<NA)? gq[tid] : 0.f;
}

// ---- one damped inexact-Newton step; returns ||g||^2 (uniform) ----
__device__ __forceinline__ float newton_step(bool exact, const float* S,
    const unsigned* mreg, float& y, float b_, float sd,
    float* yv, float* pv, float* partial, float* gq,
    float* redA, float* redB, int tid, int row, int half, bool act, float tol2){

  const bool owner = (half==0) && act;               // owner thread: tid == row < 200
  float q;
  if (exact) q = matvec_exact(S, yv, gq, tid);
  else       q = matvec_reg(mreg, yv, partial, tid, row, half, act);

  float g=0.f,d=0.f,mi=0.f,r=0.f,z=0.f,dy=0.f,pj=0.f;
  if (owner){
    g  = q - b_/y;
    d  = b_/(y*y);
    mi = 1.f/(sd+d);
    r  = -g; z = mi*r; pj = z;
    pv[tid] = z;
  }
  if (tid<256){
    float wg = wave_sum(owner? g*g : 0.f);
    float wz = wave_sum(owner? r*z : 0.f);
    if((tid&63)==0){ redA[tid>>6]=wg; redB[tid>>6]=wz; }
  }
  __syncthreads();                                   // B3
  float gg = redA[0]+redA[1]+redA[2]+redA[3];
  float rz = redB[0]+redB[1]+redB[2]+redB[3];
  if (gg <= 1e-24f) return gg;

  const float rz0 = rz;
  for (int j=0;j<CG_MAX;++j){
    float qc = matvec_reg(mreg, pv, partial, tid, row, half, act); // B1,B2
    float wpq = 0.f;
    if (owner){
      qc += d*pj;
      wpq = pj*qc;
    }
    if (tid<256){ wpq = wave_sum(wpq); if((tid&63)==0) redA[tid>>6]=wpq; }
    __syncthreads();                                 // B3'
    float pq = redA[0]+redA[1]+redA[2]+redA[3];
    float alpha = rz/pq;
    float wrz = 0.f;
    if (owner){
      dy = fmaf(alpha, pj, dy);
      r  = fmaf(-alpha, qc, r);
      z  = mi*r;
      wrz = r*z;
    }
    if (tid<256){ wrz = wave_sum(wrz); if((tid&63)==0) redB[tid>>6]=wrz; }
    __syncthreads();                                 // B4'
    float rznew = redB[0]+redB[1]+redB[2]+redB[3];
    if (rznew <= tol2*rz0 || j==CG_MAX-1) break;
    float beta = rznew/rz; rz = rznew;
    if (owner){ pj = fmaf(beta, pj, z); pv[tid] = pj; }
  }

  // damped step keeping y > 0 (reference semantics)
  float ratio = 1e30f;
  if (owner && dy < 0.f) ratio = -y/dy;
  if (tid<256){
    float w = wave_min(owner? ratio : 1e30f);
    if((tid&63)==0) redA[tid>>6]=w;
  }
  __syncthreads();
  float mr = fminf(fminf(redA[0],redA[1]),fminf(redA[2],redA[3]));
  float t  = fminf(1.f, 0.9f*mr);
  if (owner){ y = fmaxf(fmaf(t,dy,y), 1e-12f); yv[tid]=y; }
  return gg;
}

extern "C" __global__ __launch_bounds__(NTHREADS, 4)
void rb_kernel(const float* __restrict__ x,  const float* __restrict__ Sigma,
               const float* __restrict__ W1, const float* __restrict__ b1,
               const float* __restrict__ W2, const float* __restrict__ b2,
               float* __restrict__ out) {
  __shared__ __align__(16) unsigned chunkbuf[CHUNK_ROWS*CPITCH];  // 26.4 KB rotating stage
  __shared__ __align__(16) float yv[NA];
  __shared__ __align__(16) float pv[NA];
  __shared__ __align__(16) float partial[NA];
  __shared__ __align__(16) float gq[NA];
  __shared__ float xs[NF];
  __shared__ float hs[H_DIM];
  __shared__ float redA[4], redB[4], red8[NWAVES];

  const int tid  = threadIdx.x;
  const int s    = blockIdx.x;
  const int row  = tid & 255;
  const int half = tid >> 8;
  const bool act   = row < NA;
  const bool owner = (half==0) && act;
  const float* S = Sigma + (size_t)s*NA*NA;

  if (tid < NF) xs[tid] = x[s*NF + tid];
  float sd = 0.f;
  if (owner) sd = S[(size_t)row*NA + row];          // fp32 diag for Jacobi M

  // ---- stage Sigma -> bf16 packed VGPRs via rotating LDS chunk ----
  unsigned mreg[50];
  const float2* Sg2 = (const float2*)S;             // row pitch 100 float2
  #pragma unroll
  for (int c=0;c<4;++c){
    const int c0 = c*CHUNK_ROWS;
    const int nr = (c==3)? (NA-3*CHUNK_ROWS) : CHUNK_ROWS;   // 64,64,64,8
    const int cnt = nr*100;
    for (int i=tid;i<cnt;i+=NTHREADS){
      int rl = i/100, p = i - rl*100;
      float2 w = Sg2[(size_t)c0*100 + i];
      unsigned bx=__float_as_uint(w.x); bx=(bx+0x7fffu+((bx>>16)&1u))>>16;
      unsigned by=__float_as_uint(w.y); by=(by+0x7fffu+((by>>16)&1u))>>16;
      chunkbuf[rl*CPITCH + p] = bx | (by<<16);
    }
    __syncthreads();
    if (act && row>=c0 && row<c0+nr){
      const unsigned* src = chunkbuf + (row-c0)*CPITCH + half*50;
      #pragma unroll
      for (int p=0;p<50;++p) mreg[p] = src[p];
    }
    __syncthreads();
  }

  // ---- MLP ----
  if (tid < H_DIM){
    const float* w = W1 + tid*NF;
    float acc = b1[tid];
    #pragma unroll 8
    for (int j=0;j<NF;++j) acc += w[j]*xs[j];
    hs[tid] = (acc>=0.f)? acc : ALPHA_LR*acc;
  }
  __syncthreads();
  float logit = -INFINITY;
  if (tid < NA){
    const float* w = W2 + tid*H_DIM;
    float acc = b2[tid];
    #pragma unroll 8
    for (int j=0;j<H_DIM;++j) acc += w[j]*hs[j];
    logit = acc;
  }

  // ---- softmax -> b (output 2); clamp+renorm -> b_ (owner register) ----
  float mx = block_max8(logit, red8, tid);
  float e  = (tid<NA)? expf(logit-mx) : 0.f;
  float es = block_sum8(e, red8, tid);
  float bsoft = e/es;
  if (tid<NA) out[(size_t)B_SAMPLES*NA + (size_t)s*NA + tid] = bsoft;
  float bcl = fmaxf(bsoft, B_MIN_C);
  float bs  = block_sum8((tid<NA)? bcl:0.f, red8, tid);
  float b_  = bcl/bs;                                // valid on tid<NA (owners use it)

  // ---- y0 = bc / sqrt(bc^T S bc) ----
  float y = 0.f;
  if (owner) yv[tid] = b_;
  float q0 = matvec_reg(mreg, yv, partial, tid, row, half, act);
  if (tid<256){
    float wq = wave_sum(owner? b_*q0 : 0.f);
    if((tid&63)==0) redA[tid>>6]=wq;
  }
  __syncthreads();
  float quad = redA[0]+redA[1]+redA[2]+redA[3];
  if (owner){ y = b_/sqrtf(quad); yv[tid]=y; }

  // ---- phase 1: Newton, bf16 register Hessian/gradient, EW forcing ----
  float gg0=1.f, ggp=1.f;
  for (int k=0;k<N_PH1;++k){
    float tol2 = fminf(TOL2_HI, fmaxf(TOL2_LO, 4.f*ggp));
    float gg = newton_step(false, S, mreg, y, b_, sd, yv, pv, partial, gq,
                           redA, redB, tid, row, half, act, tol2);
    if (k==0) gg0 = fmaxf(gg, 1e-30f);
    ggp = gg/gg0;
    if (gg <= 1e-10f*gg0 || gg <= 1e-24f) break;
  }
  // ---- phase 2: exact fp32 gradient refinement ----
  for (int k=0;k<N_REFINE;++k){
    newton_step(true, S, mreg, y, b_, sd, yv, pv, partial, gq,
                redA, redB, tid, row, half, act, TOL2_LO);
  }

  // ---- z = y/sum(y) (output 1) ----
  __syncthreads();                                   // protect redA reuse
  if (tid<256){
    float w = wave_sum(owner? y : 0.f);
    if((tid&63)==0) redA[tid>>6]=w;
  }
  __syncthreads();
  float ys = redA[0]+redA[1]+redA[2]+redA[3];
  if (owner) out[(size_t)s*NA + tid] = y/ys;
}

extern "C" void kernel_launch(void* const* d_in, const int* in_sizes, int n_in,
                              void* d_out, int out_size, void* d_ws, size_t ws_size,
                              hipStream_t stream) {
  const float* x     = (const float*)d_in[0];
  const float* Sigma = (const float*)d_in[1];
  const float* W1    = (const float*)d_in[2];
  const float* b1    = (const float*)d_in[3];
  const float* W2    = (const float*)d_in[4];
  const float* b2    = (const float*)d_in[5];
  float* out = (float*)d_out;
  hipLaunchKernelGGL(rb_kernel, dim3(B_SAMPLES), dim3(NTHREADS), 0, stream,
                     x, Sigma, W1, b1, W2, b2, out);
}

// Round 4
// 537.427 us; speedup vs baseline: 4.4461x; 1.0609x over previous
//
#include <hip/hip_runtime.h>
#include <math.h>

#define NF        128
#define H_DIM     256
#define NA        200
#define B_SAMPLES 512
#define ALPHA_LR  0.01f
#define B_MIN_C   1e-4f

#define NTHREADS  512
#define NWAVES    8
#define ROWS_PER_WAVE 25
#define CPITCH    103               // staging pitch (dwords), odd -> conflict-free
#define CHUNK_ROWS 64

#define N_PH1     10
#define N_REFINE  2
#define CG_MAX    40
#define TOL2_LO   4e-4f
#define TOL2_HI   2.5e-2f

// ---------------- wave primitives ----------------
__device__ __forceinline__ float wave_sum(float v){
  #pragma unroll
  for(int o=32;o;o>>=1) v += __shfl_down(v,o,64);
  return v;
}
__device__ __forceinline__ float wave_min(float v){
  #pragma unroll
  for(int o=32;o;o>>=1) v = fminf(v,__shfl_down(v,o,64));
  return v;
}
__device__ __forceinline__ float wave_max(float v){
  #pragma unroll
  for(int o=32;o;o>>=1) v = fmaxf(v,__shfl_down(v,o,64));
  return v;
}
// block-wide reductions (prologue only)
__device__ __forceinline__ float block_sum8(float v, float* red8, int tid){
  int lane=tid&63, wid=tid>>6;
  __syncthreads();
  v = wave_sum(v);
  if(lane==0) red8[wid]=v;
  __syncthreads();
  float o=red8[0];
  #pragma unroll
  for(int w=1;w<NWAVES;++w) o+=red8[w];
  return o;
}
__device__ __forceinline__ float block_max8(float v, float* red8, int tid){
  int lane=tid&63, wid=tid>>6;
  __syncthreads();
  v = wave_max(v);
  if(lane==0) red8[wid]=v;
  __syncthreads();
  float o=red8[0];
  #pragma unroll
  for(int w=1;w<NWAVES;++w) o=fmaxf(o,red8[w]);
  return o;
}

// half-row bf16 register matvec accumulate (100 columns of this thread's half)
__device__ __forceinline__ float mv_half(const unsigned* mreg, const float* vv, int half){
  const float2* v2 = (const float2*)vv + half*50;
  float a0=0.f,a1=0.f,a2=0.f,a3=0.f;
  #pragma unroll
  for(int p=0;p<50;p+=2){
    unsigned u0=mreg[p], u1=mreg[p+1];
    float2 x0=v2[p], x1=v2[p+1];
    a0=fmaf(__uint_as_float(u0<<16),          x0.x,a0);
    a1=fmaf(__uint_as_float(u0&0xffff0000u),  x0.y,a1);
    a2=fmaf(__uint_as_float(u1<<16),          x1.x,a2);
    a3=fmaf(__uint_as_float(u1&0xffff0000u),  x1.y,a3);
  }
  return (a0+a1)+(a2+a3);
}

extern "C" __global__ __launch_bounds__(NTHREADS)
__attribute__((amdgpu_waves_per_eu(4, 4)))
void rb_kernel(const float* __restrict__ x,  const float* __restrict__ Sigma,
               const float* __restrict__ W1, const float* __restrict__ b1,
               const float* __restrict__ W2, const float* __restrict__ b2,
               float* __restrict__ out) {
  __shared__ __align__(16) unsigned chunkbuf[CHUNK_ROWS*CPITCH];  // 26.4 KB
  __shared__ __align__(16) float yv[NA];
  __shared__ __align__(16) float pv[NA];
  __shared__ __align__(16) float partial[NA];
  __shared__ float xs[NF];
  __shared__ float hs[H_DIM];
  __shared__ float redA[4], redB[4], redC[4], red8[NWAVES];

  const int tid  = threadIdx.x;
  const int s    = blockIdx.x;
  const int row  = tid & 255;
  const int half = tid >> 8;
  const bool act   = row < NA;
  const bool owner = (half==0) && act;          // tid < 200
  const float* S = Sigma + (size_t)s*NA*NA;

  if (tid < NF) xs[tid] = x[s*NF + tid];
  float sd = 0.f;
  if (owner) sd = S[(size_t)row*NA + row];

  // ---- stage Sigma -> bf16 packed VGPRs via rotating LDS chunk ----
  unsigned mreg[50];
  const float2* Sg2 = (const float2*)S;         // row pitch 100 float2
  for (int c=0;c<4;++c){
    const int c0 = c*CHUNK_ROWS;
    const int nr = (c==3)? (NA-3*CHUNK_ROWS) : CHUNK_ROWS;
    for (int i=tid;i<nr*100;i+=NTHREADS){
      int rl = i/100, p = i - rl*100;
      float2 w = Sg2[(size_t)c0*100 + i];
      unsigned bx=__float_as_uint(w.x); bx=(bx+0x7fffu+((bx>>16)&1u))>>16;
      unsigned by=__float_as_uint(w.y); by=(by+0x7fffu+((by>>16)&1u))>>16;
      chunkbuf[rl*CPITCH + p] = bx | (by<<16);
    }
    __syncthreads();
    if (act && row>=c0 && row<c0+nr){
      const unsigned* src = chunkbuf + (row-c0)*CPITCH + half*50;
      #pragma unroll
      for (int p=0;p<50;++p) mreg[p] = src[p];
    }
    __syncthreads();
  }

  // ---- MLP ----
  if (tid < H_DIM){
    const float* w = W1 + tid*NF;
    float acc = b1[tid];
    #pragma unroll 8
    for (int j=0;j<NF;++j) acc += w[j]*xs[j];
    hs[tid] = (acc>=0.f)? acc : ALPHA_LR*acc;
  }
  __syncthreads();
  float logit = -INFINITY;
  if (tid < NA){
    const float* w = W2 + tid*H_DIM;
    float acc = b2[tid];
    #pragma unroll 8
    for (int j=0;j<H_DIM;++j) acc += w[j]*hs[j];
    logit = acc;
  }

  // ---- softmax -> b (output 2); clamp+renorm -> b_ ----
  float mx = block_max8(logit, red8, tid);
  float e  = (tid<NA)? expf(logit-mx) : 0.f;
  float es = block_sum8(e, red8, tid);
  float bsoft = e/es;
  if (tid<NA) out[(size_t)B_SAMPLES*NA + (size_t)s*NA + tid] = bsoft;
  float bcl = fmaxf(bsoft, B_MIN_C);
  float bs  = block_sum8((tid<NA)? bcl:0.f, red8, tid);
  float b_  = bcl/bs;

  // ---- y0 = bc / sqrt(bc^T S bc) ----
  float y = 0.f;
  if (owner) yv[tid] = b_;
  __syncthreads();
  {
    float acc0 = act? mv_half(mreg, yv, half) : 0.f;
    if (half==1 && act) partial[row]=acc0;
    __syncthreads();
    float wq = 0.f;
    if (owner) wq = b_*(acc0 + partial[row]);
    if (tid<256){ wq = wave_sum(wq); if((tid&63)==0) redA[tid>>6]=wq; }
    __syncthreads();
    float quad = redA[0]+redA[1]+redA[2]+redA[3];
    if (owner){ y = b_/sqrtf(quad); yv[tid]=y; }
  }

  // ---- damped inexact Newton: phase-1 (bf16 grad) then exact-grad refine ----
  float gg0 = 1.f;
  bool  ph1done = false;
  int   nexact  = 0;
  for (int it=0; it<N_PH1+N_REFINE; ++it){
    if (nexact >= N_REFINE) break;
    const bool exact = ph1done;
    if (exact) ++nexact;

    // --- gradient matvec q = (S y)_row for owner ---
    float q = 0.f;
    if (exact){
      __syncthreads();                            // yv visible, partial reusable
      int lane=tid&63, wid=tid>>6;
      int r0=wid*ROWS_PER_WAVE;
      for (int rr=r0; rr<r0+ROWS_PER_WAVE; ++rr){
        const float* rowp = S + (size_t)rr*NA;
        float a = rowp[lane]*yv[lane] + rowp[lane+64]*yv[lane+64]
                + rowp[lane+128]*yv[lane+128];
        if (lane < NA-192) a += rowp[lane+192]*yv[lane+192];
        a = wave_sum(a);
        if (lane==0) partial[rr]=a;
      }
      __syncthreads();
      if (owner) q = partial[tid];
    } else {
      __syncthreads();                            // yv visible
      float acc = act? mv_half(mreg, yv, half) : 0.f;
      if (half==1 && act) partial[row]=acc;
      __syncthreads();
      if (owner) q = acc + partial[row];
    }

    // --- Newton body (single instantiation) ---
    float g=0.f,d=0.f,mi=0.f,r=0.f,z=0.f,dy=0.f,pj=0.f;
    if (owner){
      g  = q - b_/y;
      d  = b_/(y*y);
      mi = 1.f/(sd+d);
      r  = -g; z = mi*r; pj = z;
      pv[tid] = z;
    }
    {
      float wg = 0.f, wz = 0.f;
      if (tid<256){
        wg = wave_sum(owner? g*g : 0.f);
        wz = wave_sum(owner? r*z : 0.f);
        if((tid&63)==0){ redA[tid>>6]=wg; redB[tid>>6]=wz; }
      }
    }
    __syncthreads();
    float gg = redA[0]+redA[1]+redA[2]+redA[3];
    float rz = redB[0]+redB[1]+redB[2]+redB[3];
    if (it==0) gg0 = fmaxf(gg, 1e-30f);
    float tol2 = exact ? TOL2_LO
                       : fminf(TOL2_HI, fmaxf(TOL2_LO, 4.f*(gg/gg0)));

    if (gg > 1e-24f){
      // --- Jacobi-PCG, fused single reduction per iteration ---
      const float rz0 = rz;
      for (int j=0;j<CG_MAX;++j){
        __syncthreads();                          // B1: pv visible
        float acc = act? mv_half(mreg, pv, half) : 0.f;
        if (half==1 && act) partial[row]=acc;
        __syncthreads();                          // B2
        float qf=0.f, wpq=0.f, wrq=0.f, wqq=0.f;
        if (owner){
          qf = acc + partial[row] + d*pj;
          float u = mi*qf;
          wpq = pj*qf; wrq = r*u; wqq = qf*u;
        }
        if (tid<256){
          wpq = wave_sum(wpq); wrq = wave_sum(wrq); wqq = wave_sum(wqq);
          if((tid&63)==0){ redA[tid>>6]=wpq; redB[tid>>6]=wrq; redC[tid>>6]=wqq; }
        }
        __syncthreads();                          // B3
        float pq = redA[0]+redA[1]+redA[2]+redA[3];
        float rq = redB[0]+redB[1]+redB[2]+redB[3];
        float qq = redC[0]+redC[1]+redC[2]+redC[3];
        float alpha = rz/pq;
        float rznew = fmaxf(fmaf(alpha*alpha, qq, fmaf(-2.f*alpha, rq, rz)), 0.f);
        if (owner){
          dy = fmaf(alpha, pj, dy);
          r  = fmaf(-alpha, qf, r);
          z  = mi*r;
        }
        bool brk = (rznew <= tol2*rz0) || (j==CG_MAX-1);
        if (!brk){
          float beta = rznew/rz;
          if (owner){ pj = fmaf(beta, pj, z); pv[tid]=pj; }
        }
        rz = rznew;
        if (brk) break;
      }

      // --- damped step keeping y > 0 (reference semantics) ---
      __syncthreads();                            // protect redA before rewrite
      float ratio = 1e30f;
      if (owner && dy<0.f) ratio = -y/dy;
      if (tid<256){
        float wmn = wave_min(owner? ratio : 1e30f);
        if((tid&63)==0) redA[tid>>6]=wmn;
      }
      __syncthreads();
      float mr = fminf(fminf(redA[0],redA[1]),fminf(redA[2],redA[3]));
      float t  = fminf(1.f, 0.9f*mr);
      if (owner){ y = fmaxf(fmaf(t,dy,y), 1e-12f); yv[tid]=y; }
    }

    if (!exact && (gg <= 1e-8f*gg0 || it+1 >= N_PH1)) ph1done = true;
  }

  // ---- z = y/sum(y) (output 1) ----
  __syncthreads();                                // protect redA
  if (tid<256){
    float w = wave_sum(owner? y : 0.f);
    if((tid&63)==0) redA[tid>>6]=w;
  }
  __syncthreads();
  float ys = redA[0]+redA[1]+redA[2]+redA[3];
  if (owner) out[(size_t)s*NA + tid] = y/ys;
}

extern "C" void kernel_launch(void* const* d_in, const int* in_sizes, int n_in,
                              void* d_out, int out_size, void* d_ws, size_t ws_size,
                              hipStream_t stream) {
  const float* x     = (const float*)d_in[0];
  const float* Sigma = (const float*)d_in[1];
  const float* W1    = (const float*)d_in[2];
  const float* b1    = (const float*)d_in[3];
  const float* W2    = (const float*)d_in[4];
  const float* b2    = (const float*)d_in[5];
  float* out = (float*)d_out;
  hipLaunchKernelGGL(rb_kernel, dim3(B_SAMPLES), dim3(NTHREADS), 0, stream,
                     x, Sigma, W1, b1, W2, b2, out);
}